// Round 11
// baseline (158.684 us; speedup 1.0000x reference)
//
#include <hip/hip_runtime.h>
#include <math.h>

#define B 4
#define N 256
#define DIN 4
#define D 64
#define NH 4
#define NL 2
#define DH 16

constexpr float EPS = 1e-5f;
constexpr float SLOPE = 0.01f;

// ---------------------------------------------------------------------------
// Register M/C projection (redundant per wave via butterfly; proven R5-R10).
// ---------------------------------------------------------------------------
__device__ __forceinline__ void mc_proj(
    const float* __restrict__ W1, const float* __restrict__ b1,
    const float* __restrict__ mw, const float* __restrict__ mb,
    int lane, float* Mreg /*16*/, float* Creg /*4*/) {
    float w1v[4];
#pragma unroll
    for (int kk = 0; kk < 4; ++kk) w1v[kk] = W1[kk * D + lane];
    float b1v = b1[lane];
#pragma unroll
    for (int n = 0; n < 4; ++n) {
        float mwv = mw[n * D + lane];
        float p0 = w1v[0] * mwv, p1 = w1v[1] * mwv;
        float p2 = w1v[2] * mwv, p3 = w1v[3] * mwv;
        float pc = b1v * mwv;
#pragma unroll
        for (int off = 32; off > 0; off >>= 1) {
            p0 += __shfl_xor(p0, off); p1 += __shfl_xor(p1, off);
            p2 += __shfl_xor(p2, off); p3 += __shfl_xor(p3, off);
            pc += __shfl_xor(pc, off);
        }
        Mreg[n * 4 + 0] = p0; Mreg[n * 4 + 1] = p1;
        Mreg[n * 4 + 2] = p2; Mreg[n * 4 + 3] = p3;
        Creg[n] = pc + mb[n];
    }
}

// ---------------------------------------------------------------------------
// P1: rowsum (R10, unchanged). grid 256, block 512.
// ---------------------------------------------------------------------------
__global__ void __launch_bounds__(512) k_rowsum(
    const float* __restrict__ feature, const float* __restrict__ W1,
    const float* __restrict__ b1, const float* __restrict__ mw,
    const float* __restrict__ mb, float* __restrict__ rs,
    float* __restrict__ bnacc /* [128]: macc|sacc */) {
    __shared__ float part[32];
    int t = threadIdx.x;
    int lane = t & 63, w = t >> 6;
    int cb = blockIdx.x;
    if (cb == 0 && t < 128) bnacc[t] = 0.f;

    int r = w & 3, mh = w >> 2;
    int bi = cb * 4 + r;
    const float4* fb = (const float4*)(feature) + (size_t)bi * N;
    float4 f0 = fb[lane + 64 * (mh * 2 + 0)];
    float4 f1 = fb[lane + 64 * (mh * 2 + 1)];

    float Mreg[16], Creg[4];
    mc_proj(W1, b1, mw, mb, lane, Mreg, Creg);

    float sn[4] = {0.f, 0.f, 0.f, 0.f};
#pragma unroll
    for (int mm = 0; mm < 2; ++mm) {
        float4 f = (mm == 0) ? f0 : f1;
#pragma unroll
        for (int n = 0; n < 4; ++n) {
            float s = Creg[n] + f.x * Mreg[n*4+0] + f.y * Mreg[n*4+1]
                              + f.z * Mreg[n*4+2] + f.w * Mreg[n*4+3];
            s = (s >= 0.f) ? s : SLOPE * s;
            sn[n] += __expf(s);
        }
    }
#pragma unroll
    for (int n = 0; n < 4; ++n)
#pragma unroll
        for (int off = 32; off > 0; off >>= 1) sn[n] += __shfl_xor(sn[n], off);
    if (lane == 0) {
#pragma unroll
        for (int n = 0; n < 4; ++n) part[w * 4 + n] = sn[n];
    }
    __syncthreads();
    if (t < 16) {
        int rr = t >> 2, n = t & 3;
        rs[((size_t)(cb * 4 + rr)) * 4 + n] = part[rr * 4 + n] + part[(rr + 4) * 4 + n];
    }
}

// ---------------------------------------------------------------------------
// P2: aggregate + h projection + BN partials (R10, unchanged). grid 256x512.
// ---------------------------------------------------------------------------
__global__ void __launch_bounds__(512) k_aggregate(
    const float* __restrict__ feature, const float* __restrict__ W1,
    const float* __restrict__ b1, const float* __restrict__ mw,
    const float* __restrict__ mb, const float* __restrict__ rs,
    float* __restrict__ h, float* __restrict__ bnacc) {
    __shared__ float part[8][10];
    __shared__ float gacc[20];
    __shared__ float hs[4][D];
    int t = threadIdx.x;
    int lane = t & 63, w = t >> 6;
    int cb = blockIdx.x;

    int b = cb >> 6, j0 = (cb & 63) * 4;
    int i = t & 255, jh = t >> 8;
    const float4* fb = (const float4*)(feature) + ((size_t)(b * N + i) * N + j0 + jh * 2);
    float4 f[2];
    f[0] = fb[0];
    f[1] = fb[1];
    float4 r4 = *(const float4*)(rs + (size_t)(b * N + i) * 4);

    float Mreg[16], Creg[4];
    mc_proj(W1, b1, mw, mb, lane, Mreg, Creg);
    float w1v[4];
#pragma unroll
    for (int kk = 0; kk < 4; ++kk) w1v[kk] = W1[kk * D + lane];
    float b1v = b1[lane];

    float rinv[4] = {1.f / r4.x, 1.f / r4.y, 1.f / r4.z, 1.f / r4.w};
    float acc[2][5];
#pragma unroll
    for (int jj = 0; jj < 2; ++jj) {
        float wbar = 0.f;
#pragma unroll
        for (int n = 0; n < 4; ++n) {
            float s = Creg[n] + f[jj].x * Mreg[n*4+0] + f[jj].y * Mreg[n*4+1]
                              + f[jj].z * Mreg[n*4+2] + f[jj].w * Mreg[n*4+3];
            s = (s >= 0.f) ? s : SLOPE * s;
            wbar += __expf(s) * rinv[n];
        }
        wbar *= 0.25f;
        acc[jj][0] = wbar * f[jj].x; acc[jj][1] = wbar * f[jj].y;
        acc[jj][2] = wbar * f[jj].z; acc[jj][3] = wbar * f[jj].w;
        acc[jj][4] = wbar;
    }
#pragma unroll
    for (int jj = 0; jj < 2; ++jj)
#pragma unroll
        for (int c = 0; c < 5; ++c)
#pragma unroll
            for (int off = 32; off > 0; off >>= 1) acc[jj][c] += __shfl_xor(acc[jj][c], off);
    if (lane == 0) {
#pragma unroll
        for (int jj = 0; jj < 2; ++jj)
#pragma unroll
            for (int c = 0; c < 5; ++c) part[w][jj * 5 + c] = acc[jj][c];
    }
    __syncthreads();
    if (t < 20) {
        int jj = t / 5, c = t - jj * 5;
        int g = jj >> 1, jjl = jj & 1;
        gacc[t] = part[g*4+0][jjl*5+c] + part[g*4+1][jjl*5+c]
                + part[g*4+2][jjl*5+c] + part[g*4+3][jjl*5+c];
    }
    __syncthreads();
    if (t < 256) {
        float hv = gacc[w * 5 + 4] * b1v;
#pragma unroll
        for (int kk = 0; kk < 4; ++kk) hv += gacc[w * 5 + kk] * w1v[kk];
        h[((size_t)(b * N + j0 + w)) * D + lane] = hv;
        hs[w][lane] = hv;
    }
    __syncthreads();
    if (t < 64) {
        float s = hs[0][lane] + hs[1][lane] + hs[2][lane] + hs[3][lane];
        float sq = hs[0][lane]*hs[0][lane] + hs[1][lane]*hs[1][lane]
                 + hs[2][lane]*hs[2][lane] + hs[3][lane]*hs[3][lane];
        atomicAdd(bnacc + lane, s);
        atomicAdd(bnacc + D + lane, sq);
    }
}

// ---------------------------------------------------------------------------
// P3: BN finalize + QKV layer 0 — BARRIER-FREE. grid (B, N/4) x 256.
// One wave = one token; lane = channel; activations broadcast via __shfl
// (v_readlane with constant lanes — no LDS). No __syncthreads -> no
// compiler-inserted s_waitcnt vmcnt(0) drains of in-flight weight loads.
// ---------------------------------------------------------------------------
__global__ void __launch_bounds__(256, 2) k_qkv0(
    const float* __restrict__ h, const float* __restrict__ bnacc,
    const float* __restrict__ bn_g, const float* __restrict__ bn_b,
    const float* __restrict__ Wq, const float* __restrict__ bq,
    const float* __restrict__ Wk, const float* __restrict__ bk,
    const float* __restrict__ Wv, const float* __restrict__ bv,
    float* __restrict__ x, float* __restrict__ q,
    float* __restrict__ k, float* __restrict__ v) {
    int t = threadIdx.x, lane = t & 63, w = t >> 6, ch = lane;
    int b = blockIdx.x, n = blockIdx.y * 4 + w;
    size_t xi = ((size_t)(b * N + n)) * D + ch;

    float mean = bnacc[ch] * (1.0f / (B * N));
    float var = bnacc[D + ch] * (1.0f / (B * N)) - mean * mean;
    float inv = rsqrtf(var + EPS);
    float xv = bn_g[ch] * (h[xi] - mean) * inv + bn_b[ch];
    x[xi] = xv;

    float aq = bq[ch], ak = bk[ch], av = bv[ch];
#pragma unroll
    for (int kk = 0; kk < D; ++kk) {
        float xx = __shfl(xv, kk);
        aq += xx * Wq[kk * D + ch];
        ak += xx * Wk[kk * D + ch];
        av += xx * Wv[kk * D + ch];
    }
    int head = ch >> 4, dh = ch & (DH - 1);
    size_t oidx = (((size_t)(b * NH + head)) * N + n) * DH + dh;
    q[oidx] = aq; k[oidx] = ak; v[oidx] = av;
}

// Attention single-token helpers (2-deep pipelined K/V stream, R10-proven).
#define ATT_LOAD1(Kx, Vx, cc)                                                  \
    {                                                                          \
        const float4* kp4 = (const float4*)(kb + (size_t)((cc) * 64 + lane) * DH); \
        const float4* vp4 = (const float4*)(vb + (size_t)((cc) * 64 + lane) * DH); \
        _Pragma("unroll")                                                      \
        for (int c = 0; c < 4; ++c) { Kx[c] = kp4[c]; Vx[c] = vp4[c]; }        \
    }

#define ATT_CHUNK1(Kx, Vx)                                                     \
    {                                                                          \
        float s = 0.f;                                                         \
        _Pragma("unroll")                                                      \
        for (int c = 0; c < 4; ++c)                                            \
            s += qv[c].x * Kx[c].x + qv[c].y * Kx[c].y +                       \
                 qv[c].z * Kx[c].z + qv[c].w * Kx[c].w;                        \
        float p = __expf(s * 0.25f);                                           \
        l += p;                                                                \
        _Pragma("unroll")                                                      \
        for (int c = 0; c < 4; ++c) {                                          \
            o[4*c+0] += p * Vx[c].x; o[4*c+1] += p * Vx[c].y;                  \
            o[4*c+2] += p * Vx[c].z; o[4*c+3] += p * Vx[c].w;                  \
        }                                                                      \
    }

// ---------------------------------------------------------------------------
// D3/D4: layer tail — BARRIER-FREE, LDS-FREE. grid (B, N/4) x 256.
// One wave = one token. Attention: heads sequential; lane = key; butterfly
// all-reduce gives every lane the full softmax/PV sums, then a static
// 16-way select lands attv at lane = channel. All matmuls are 64-wide
// shuffle-broadcast dots with split accumulators. Zero __syncthreads ->
// zero forced vmcnt(0) drains; each wave's ~600 weight loads pipeline free.
// ---------------------------------------------------------------------------
template <bool FUSE>
__global__ void __launch_bounds__(256, 2) k_layer(
    const float* __restrict__ q, const float* __restrict__ k,
    const float* __restrict__ v,
    const float* __restrict__ Wo, const float* __restrict__ bo,
    const float* __restrict__ ln1g, const float* __restrict__ ln1b,
    const float* __restrict__ Wff1, const float* __restrict__ bff1,
    const float* __restrict__ Wff2, const float* __restrict__ bff2,
    const float* __restrict__ ln2g, const float* __restrict__ ln2b,
    const float* __restrict__ Wqn, const float* __restrict__ bqn,
    const float* __restrict__ Wkn, const float* __restrict__ bkn,
    const float* __restrict__ Wvn, const float* __restrict__ bvn,
    float* __restrict__ qo, float* __restrict__ ko, float* __restrict__ vo,
    float* __restrict__ x) {
    int t = threadIdx.x, lane = t & 63, w = t >> 6, ch = lane;
    int b = blockIdx.x, n = blockIdx.y * 4 + w;
    size_t xidx = ((size_t)b * N + n) * D + ch;
    float xv = x[xidx];
    float bo_r = bo[ch], l1g = ln1g[ch], l1b = ln1b[ch];
    float bf1a = bff1[ch], bf1b = bff1[D + ch];
    float bf2_r = bff2[ch], l2g = ln2g[ch], l2b = ln2b[ch];
    float bq_r = 0.f, bk_r = 0.f, bv_r = 0.f;
    if (FUSE) { bq_r = bqn[ch]; bk_r = bkn[ch]; bv_r = bvn[ch]; }

    // ---- attention: heads sequential, lane = key, all-reduce softmax ----
    float attv = 0.f;
#pragma unroll
    for (int h = 0; h < NH; ++h) {
        const float* kb = k + (size_t)(b * NH + h) * N * DH;
        const float* vb = v + (size_t)(b * NH + h) * N * DH;
        const float4* qp = (const float4*)(q + ((size_t)(b * NH + h) * N + n) * DH);
        float4 KA[4], VA[4], KB[4], VB[4];
        ATT_LOAD1(KA, VA, 0);
        ATT_LOAD1(KB, VB, 1);
        float4 qv[4];
#pragma unroll
        for (int c = 0; c < 4; ++c) qv[c] = qp[c];
        float o[DH];
#pragma unroll
        for (int d = 0; d < DH; ++d) o[d] = 0.f;
        float l = 0.f;
        ATT_CHUNK1(KA, VA);
        ATT_LOAD1(KA, VA, 2);
        ATT_CHUNK1(KB, VB);
        ATT_LOAD1(KB, VB, 3);
        ATT_CHUNK1(KA, VA);
        ATT_CHUNK1(KB, VB);
#pragma unroll
        for (int off = 32; off > 0; off >>= 1) l += __shfl_xor(l, off);
#pragma unroll
        for (int d = 0; d < DH; ++d)
#pragma unroll
            for (int off = 32; off > 0; off >>= 1) o[d] += __shfl_xor(o[d], off);
        float rl = 1.f / l;
        if ((ch >> 4) == h) {   // butterfly = allreduce: every lane has o[d]
            float sel = o[0];
#pragma unroll
            for (int d = 1; d < DH; ++d)
                if ((ch & 15) == d) sel = o[d];
            attv = sel * rl;
        }
    }

    // ---- O-proj: 64-wide shuffle-broadcast dot ----
    float a0 = bo_r, a1 = 0.f, a2 = 0.f, a3 = 0.f;
#pragma unroll
    for (int kk = 0; kk < D; kk += 4) {
        a0 += __shfl(attv, kk + 0) * Wo[(kk + 0) * D + ch];
        a1 += __shfl(attv, kk + 1) * Wo[(kk + 1) * D + ch];
        a2 += __shfl(attv, kk + 2) * Wo[(kk + 2) * D + ch];
        a3 += __shfl(attv, kk + 3) * Wo[(kk + 3) * D + ch];
    }
    float r = xv + (a0 + a1) + (a2 + a3);

    // ---- LN1 (butterfly) ----
    float s1 = r, sq1 = r * r;
#pragma unroll
    for (int off = 32; off > 0; off >>= 1) {
        s1 += __shfl_xor(s1, off);
        sq1 += __shfl_xor(sq1, off);
    }
    float mean1 = s1 * (1.0f / D), var1 = sq1 * (1.0f / D) - mean1 * mean1;
    float x1 = l1g * (r - mean1) * rsqrtf(var1 + EPS) + l1b;

    // ---- FFN1: both halves share the shuffles ----
    float u0 = bf1a, u1 = 0.f, g0 = bf1b, g1 = 0.f;
#pragma unroll
    for (int kk = 0; kk < D; kk += 2) {
        float xa = __shfl(x1, kk), xb = __shfl(x1, kk + 1);
        u0 += xa * Wff1[kk * 2 * D + ch];
        g0 += xa * Wff1[kk * 2 * D + D + ch];
        u1 += xb * Wff1[(kk + 1) * 2 * D + ch];
        g1 += xb * Wff1[(kk + 1) * 2 * D + D + ch];
    }
    float f1lo = fmaxf(u0 + u1, 0.f), f1hi = fmaxf(g0 + g1, 0.f);

    // ---- FFN2: 128-wide dot (two 64-wide halves) ----
    float e0 = bf2_r, e1 = 0.f, e2 = 0.f, e3 = 0.f;
#pragma unroll
    for (int kk = 0; kk < D; kk += 2) {
        e0 += __shfl(f1lo, kk) * Wff2[kk * D + ch];
        e1 += __shfl(f1lo, kk + 1) * Wff2[(kk + 1) * D + ch];
        e2 += __shfl(f1hi, kk) * Wff2[(D + kk) * D + ch];
        e3 += __shfl(f1hi, kk + 1) * Wff2[(D + kk + 1) * D + ch];
    }
    float o2 = (e0 + e1) + (e2 + e3);
    float r2 = x1 + o2;

    // ---- LN2 (butterfly) ----
    float s2 = r2, sq2 = r2 * r2;
#pragma unroll
    for (int off = 32; off > 0; off >>= 1) {
        s2 += __shfl_xor(s2, off);
        sq2 += __shfl_xor(sq2, off);
    }
    float mean2 = s2 * (1.0f / D), var2 = sq2 * (1.0f / D) - mean2 * mean2;
    float xnew = l2g * (r2 - mean2) * rsqrtf(var2 + EPS) + l2b;
    x[xidx] = xnew;

    // ---- fused next-layer QKV (3 dots share the shuffles) ----
    if (FUSE) {
        float aq = bq_r, ak = bk_r, av = bv_r;
#pragma unroll
        for (int kk = 0; kk < D; ++kk) {
            float xx = __shfl(xnew, kk);
            aq += xx * Wqn[kk * D + ch];
            ak += xx * Wkn[kk * D + ch];
            av += xx * Wvn[kk * D + ch];
        }
        int head = ch >> 4, dh = ch & (DH - 1);
        size_t oidx = (((size_t)(b * NH + head)) * N + n) * DH + dh;
        qo[oidx] = aq; ko[oidx] = ak; vo[oidx] = av;
    }
}

extern "C" void kernel_launch(void* const* d_in, const int* in_sizes, int n_in,
                              void* d_out, int out_size, void* d_ws, size_t ws_size,
                              hipStream_t stream) {
    const float* feature = (const float*)d_in[0];
    const float* W1   = (const float*)d_in[1];
    const float* b1   = (const float*)d_in[2];
    const float* mw   = (const float*)d_in[3];
    const float* mb   = (const float*)d_in[4];
    const float* bn_g = (const float*)d_in[5];
    const float* bn_b = (const float*)d_in[6];
    const float* Wq   = (const float*)d_in[7];
    const float* bq   = (const float*)d_in[8];
    const float* Wk   = (const float*)d_in[9];
    const float* bk   = (const float*)d_in[10];
    const float* Wv   = (const float*)d_in[11];
    const float* bv   = (const float*)d_in[12];
    const float* Wo   = (const float*)d_in[13];
    const float* bo   = (const float*)d_in[14];
    const float* ln1g = (const float*)d_in[15];
    const float* ln1b = (const float*)d_in[16];
    const float* Wff1 = (const float*)d_in[17];
    const float* bff1 = (const float*)d_in[18];
    const float* Wff2 = (const float*)d_in[19];
    const float* bff2 = (const float*)d_in[20];
    const float* ln2g = (const float*)d_in[21];
    const float* ln2b = (const float*)d_in[22];

    float* ws    = (float*)d_ws;
    float* rs    = ws;                     // B*N*NH = 4096
    float* bnacc = rs + B * N * NH;        // 128
    float* h     = bnacc + 128;            // B*N*D
    float* q     = h + B * N * D;          // B*N*D
    float* k0    = q + B * N * D;
    float* v0    = k0 + B * N * D;
    float* k1    = v0 + B * N * D;
    float* v1    = k1 + B * N * D;
    float* x     = (float*)d_out;          // running (B,N,D) activation

    k_rowsum<<<256, 512, 0, stream>>>(feature, W1, b1, mw, mb, rs, bnacc);
    k_aggregate<<<256, 512, 0, stream>>>(feature, W1, b1, mw, mb, rs, h, bnacc);
    k_qkv0<<<dim3(B, N / 4), 256, 0, stream>>>(h, bnacc, bn_g, bn_b,
                                               Wq, bq, Wk, bk, Wv, bv, x, q, k0, v0);
    // layer 0 (fused layer-1 QKV into q / k1 / v1), then layer 1
    k_layer<true><<<dim3(B, N / 4), 256, 0, stream>>>(q, k0, v0,
        Wo, bo, ln1g, ln1b, Wff1, bff1, Wff2, bff2, ln2g, ln2b,
        Wq + (size_t)D * D, bq + D, Wk + (size_t)D * D, bk + D,
        Wv + (size_t)D * D, bv + D, q, k1, v1, x);
    k_layer<false><<<dim3(B, N / 4), 256, 0, stream>>>(q, k1, v1,
        Wo + (size_t)D * D, bo + D, ln1g + D, ln1b + D,
        Wff1 + (size_t)D * 2 * D, bff1 + 2 * D,
        Wff2 + (size_t)2 * D * D, bff2 + D, ln2g + D, ln2b + D,
        nullptr, nullptr, nullptr, nullptr, nullptr, nullptr,
        nullptr, nullptr, nullptr, x);
}

// Round 12
// 147.216 us; speedup vs baseline: 1.0779x; 1.0779x over previous
//
#include <hip/hip_runtime.h>
#include <math.h>

#define B 4
#define N 256
#define DIN 4
#define D 64
#define NH 4
#define NL 2
#define DH 16

constexpr float EPS = 1e-5f;
constexpr float SLOPE = 0.01f;

// ---------------------------------------------------------------------------
// Register M/C projection (redundant per wave via butterfly; proven R5-R10).
// ---------------------------------------------------------------------------
__device__ __forceinline__ void mc_proj(
    const float* __restrict__ W1, const float* __restrict__ b1,
    const float* __restrict__ mw, const float* __restrict__ mb,
    int lane, float* Mreg /*16*/, float* Creg /*4*/) {
    float w1v[4];
#pragma unroll
    for (int kk = 0; kk < 4; ++kk) w1v[kk] = W1[kk * D + lane];
    float b1v = b1[lane];
#pragma unroll
    for (int n = 0; n < 4; ++n) {
        float mwv = mw[n * D + lane];
        float p0 = w1v[0] * mwv, p1 = w1v[1] * mwv;
        float p2 = w1v[2] * mwv, p3 = w1v[3] * mwv;
        float pc = b1v * mwv;
#pragma unroll
        for (int off = 32; off > 0; off >>= 1) {
            p0 += __shfl_xor(p0, off); p1 += __shfl_xor(p1, off);
            p2 += __shfl_xor(p2, off); p3 += __shfl_xor(p3, off);
            pc += __shfl_xor(pc, off);
        }
        Mreg[n * 4 + 0] = p0; Mreg[n * 4 + 1] = p1;
        Mreg[n * 4 + 2] = p2; Mreg[n * 4 + 3] = p3;
        Creg[n] = pc + mb[n];
    }
}

// ---------------------------------------------------------------------------
// P1: rowsum (R10, unchanged). grid 256, block 512.
// ---------------------------------------------------------------------------
__global__ void __launch_bounds__(512) k_rowsum(
    const float* __restrict__ feature, const float* __restrict__ W1,
    const float* __restrict__ b1, const float* __restrict__ mw,
    const float* __restrict__ mb, float* __restrict__ rs,
    float* __restrict__ bnacc /* [128]: macc|sacc */) {
    __shared__ float part[32];
    int t = threadIdx.x;
    int lane = t & 63, w = t >> 6;
    int cb = blockIdx.x;
    if (cb == 0 && t < 128) bnacc[t] = 0.f;

    int r = w & 3, mh = w >> 2;
    int bi = cb * 4 + r;
    const float4* fb = (const float4*)(feature) + (size_t)bi * N;
    float4 f0 = fb[lane + 64 * (mh * 2 + 0)];
    float4 f1 = fb[lane + 64 * (mh * 2 + 1)];

    float Mreg[16], Creg[4];
    mc_proj(W1, b1, mw, mb, lane, Mreg, Creg);

    float sn[4] = {0.f, 0.f, 0.f, 0.f};
#pragma unroll
    for (int mm = 0; mm < 2; ++mm) {
        float4 f = (mm == 0) ? f0 : f1;
#pragma unroll
        for (int n = 0; n < 4; ++n) {
            float s = Creg[n] + f.x * Mreg[n*4+0] + f.y * Mreg[n*4+1]
                              + f.z * Mreg[n*4+2] + f.w * Mreg[n*4+3];
            s = (s >= 0.f) ? s : SLOPE * s;
            sn[n] += __expf(s);
        }
    }
#pragma unroll
    for (int n = 0; n < 4; ++n)
#pragma unroll
        for (int off = 32; off > 0; off >>= 1) sn[n] += __shfl_xor(sn[n], off);
    if (lane == 0) {
#pragma unroll
        for (int n = 0; n < 4; ++n) part[w * 4 + n] = sn[n];
    }
    __syncthreads();
    if (t < 16) {
        int rr = t >> 2, n = t & 3;
        rs[((size_t)(cb * 4 + rr)) * 4 + n] = part[rr * 4 + n] + part[(rr + 4) * 4 + n];
    }
}

// ---------------------------------------------------------------------------
// P2: aggregate + h projection + BN partials (R10, unchanged). grid 256x512.
// ---------------------------------------------------------------------------
__global__ void __launch_bounds__(512) k_aggregate(
    const float* __restrict__ feature, const float* __restrict__ W1,
    const float* __restrict__ b1, const float* __restrict__ mw,
    const float* __restrict__ mb, const float* __restrict__ rs,
    float* __restrict__ h, float* __restrict__ bnacc) {
    __shared__ float part[8][10];
    __shared__ float gacc[20];
    __shared__ float hs[4][D];
    int t = threadIdx.x;
    int lane = t & 63, w = t >> 6;
    int cb = blockIdx.x;

    int b = cb >> 6, j0 = (cb & 63) * 4;
    int i = t & 255, jh = t >> 8;
    const float4* fb = (const float4*)(feature) + ((size_t)(b * N + i) * N + j0 + jh * 2);
    float4 f[2];
    f[0] = fb[0];
    f[1] = fb[1];
    float4 r4 = *(const float4*)(rs + (size_t)(b * N + i) * 4);

    float Mreg[16], Creg[4];
    mc_proj(W1, b1, mw, mb, lane, Mreg, Creg);
    float w1v[4];
#pragma unroll
    for (int kk = 0; kk < 4; ++kk) w1v[kk] = W1[kk * D + lane];
    float b1v = b1[lane];

    float rinv[4] = {1.f / r4.x, 1.f / r4.y, 1.f / r4.z, 1.f / r4.w};
    float acc[2][5];
#pragma unroll
    for (int jj = 0; jj < 2; ++jj) {
        float wbar = 0.f;
#pragma unroll
        for (int n = 0; n < 4; ++n) {
            float s = Creg[n] + f[jj].x * Mreg[n*4+0] + f[jj].y * Mreg[n*4+1]
                              + f[jj].z * Mreg[n*4+2] + f[jj].w * Mreg[n*4+3];
            s = (s >= 0.f) ? s : SLOPE * s;
            wbar += __expf(s) * rinv[n];
        }
        wbar *= 0.25f;
        acc[jj][0] = wbar * f[jj].x; acc[jj][1] = wbar * f[jj].y;
        acc[jj][2] = wbar * f[jj].z; acc[jj][3] = wbar * f[jj].w;
        acc[jj][4] = wbar;
    }
#pragma unroll
    for (int jj = 0; jj < 2; ++jj)
#pragma unroll
        for (int c = 0; c < 5; ++c)
#pragma unroll
            for (int off = 32; off > 0; off >>= 1) acc[jj][c] += __shfl_xor(acc[jj][c], off);
    if (lane == 0) {
#pragma unroll
        for (int jj = 0; jj < 2; ++jj)
#pragma unroll
            for (int c = 0; c < 5; ++c) part[w][jj * 5 + c] = acc[jj][c];
    }
    __syncthreads();
    if (t < 20) {
        int jj = t / 5, c = t - jj * 5;
        int g = jj >> 1, jjl = jj & 1;
        gacc[t] = part[g*4+0][jjl*5+c] + part[g*4+1][jjl*5+c]
                + part[g*4+2][jjl*5+c] + part[g*4+3][jjl*5+c];
    }
    __syncthreads();
    if (t < 256) {
        float hv = gacc[w * 5 + 4] * b1v;
#pragma unroll
        for (int kk = 0; kk < 4; ++kk) hv += gacc[w * 5 + kk] * w1v[kk];
        h[((size_t)(b * N + j0 + w)) * D + lane] = hv;
        hs[w][lane] = hv;
    }
    __syncthreads();
    if (t < 64) {
        float s = hs[0][lane] + hs[1][lane] + hs[2][lane] + hs[3][lane];
        float sq = hs[0][lane]*hs[0][lane] + hs[1][lane]*hs[1][lane]
                 + hs[2][lane]*hs[2][lane] + hs[3][lane]*hs[3][lane];
        atomicAdd(bnacc + lane, s);
        atomicAdd(bnacc + D + lane, sq);
    }
}

// ---------------------------------------------------------------------------
// P3: BN finalize + QKV layer 0 (R10 body, unchanged). grid (B, N/2) x 256.
// ---------------------------------------------------------------------------
__global__ void __launch_bounds__(256, 2) k_qkv0(
    const float* __restrict__ h, const float* __restrict__ bnacc,
    const float* __restrict__ bn_g, const float* __restrict__ bn_b,
    const float* __restrict__ Wq, const float* __restrict__ bq,
    const float* __restrict__ Wk, const float* __restrict__ bk,
    const float* __restrict__ Wv, const float* __restrict__ bv,
    float* __restrict__ x, float* __restrict__ q,
    float* __restrict__ k, float* __restrict__ v) {
    __shared__ float xs[2][D];
    __shared__ float pp[4][2][192];
    int t = threadIdx.x, lane = t & 63, w = t >> 6, ch = lane;
    int b = blockIdx.x, n0 = blockIdx.y * 2;

    float wq[16], wk[16], wv[16];
#pragma unroll
    for (int i = 0; i < 16; ++i) {
        int kk = w * 16 + i;
        wq[i] = Wq[kk * D + ch];
        wk[i] = Wk[kk * D + ch];
        wv[i] = Wv[kk * D + ch];
    }
    float mean = bnacc[ch] * (1.0f / (B * N));
    float var = bnacc[D + ch] * (1.0f / (B * N)) - mean * mean;
    float inv = rsqrtf(var + EPS);
    size_t xi0 = ((size_t)(b * N + n0)) * D + ch;
    float xv0 = bn_g[ch] * (h[xi0] - mean) * inv + bn_b[ch];
    float xv1 = bn_g[ch] * (h[xi0 + D] - mean) * inv + bn_b[ch];
    if (w == 0) { x[xi0] = xv0; xs[0][ch] = xv0; }
    if (w == 1) { x[xi0 + D] = xv1; xs[1][ch] = xv1; }
    __syncthreads();

    float aq0=0.f, ak0=0.f, av0=0.f, aq1=0.f, ak1=0.f, av1=0.f;
#pragma unroll
    for (int i = 0; i < 16; ++i) {
        int kk = w * 16 + i;
        float xx0 = xs[0][kk], xx1 = xs[1][kk];
        aq0 += xx0 * wq[i]; ak0 += xx0 * wk[i]; av0 += xx0 * wv[i];
        aq1 += xx1 * wq[i]; ak1 += xx1 * wk[i]; av1 += xx1 * wv[i];
    }
    pp[w][0][ch] = aq0; pp[w][0][64 + ch] = ak0; pp[w][0][128 + ch] = av0;
    pp[w][1][ch] = aq1; pp[w][1][64 + ch] = ak1; pp[w][1][128 + ch] = av1;
    __syncthreads();
    if (w < 3) {
        int o = w * 64;
        int head = ch >> 4, dh = ch & (DH - 1);
#pragma unroll
        for (int tk = 0; tk < 2; ++tk) {
            float val = pp[0][tk][o+ch] + pp[1][tk][o+ch] + pp[2][tk][o+ch] + pp[3][tk][o+ch];
            size_t oidx = (((size_t)(b * NH + head)) * N + (n0 + tk)) * DH + dh;
            if (w == 0) q[oidx] = val + bq[ch];
            else if (w == 1) k[oidx] = val + bk[ch];
            else v[oidx] = val + bv[ch];
        }
    }
}

// Per-chunk attention compute on statically-named K/V buffers (R10-proven).
#define ATT_CHUNK(Kx, Vx)                                                      \
    {                                                                          \
        float s0 = 0.f, s1 = 0.f;                                              \
        _Pragma("unroll")                                                      \
        for (int c = 0; c < 4; ++c) {                                          \
            s0 += qv0[c].x * Kx[c].x + qv0[c].y * Kx[c].y +                    \
                  qv0[c].z * Kx[c].z + qv0[c].w * Kx[c].w;                     \
            s1 += qv1[c].x * Kx[c].x + qv1[c].y * Kx[c].y +                    \
                  qv1[c].z * Kx[c].z + qv1[c].w * Kx[c].w;                     \
        }                                                                      \
        float p0 = __expf(s0 * 0.25f);                                         \
        float p1 = __expf(s1 * 0.25f);                                         \
        l0 += p0; l1 += p1;                                                    \
        _Pragma("unroll")                                                      \
        for (int c = 0; c < 4; ++c) {                                          \
            o0[4*c+0] += p0 * Vx[c].x; o0[4*c+1] += p0 * Vx[c].y;              \
            o0[4*c+2] += p0 * Vx[c].z; o0[4*c+3] += p0 * Vx[c].w;              \
            o1[4*c+0] += p1 * Vx[c].x; o1[4*c+1] += p1 * Vx[c].y;              \
            o1[4*c+2] += p1 * Vx[c].z; o1[4*c+3] += p1 * Vx[c].w;              \
        }                                                                      \
    }

#define ATT_LOAD(Kx, Vx, cc)                                                   \
    {                                                                          \
        const float4* kp4 = (const float4*)(kb + (size_t)((cc) * 64 + lane) * DH); \
        const float4* vp4 = (const float4*)(vb + (size_t)((cc) * 64 + lane) * DH); \
        _Pragma("unroll")                                                      \
        for (int c = 0; c < 4; ++c) { Kx[c] = kp4[c]; Vx[c] = vp4[c]; }        \
    }

// ---------------------------------------------------------------------------
// D3/D4: layer tail. R10's pipelined-attention body + ALL phase weights
// (wo/wf1a/wf1b/wf2 = 80 VGPRs) prefetched at kernel entry, materialization
// pinned by empty-asm anchors after the attention chunks so the compiler
// cannot sink the loads back to their uses (which would re-create a full
// load-latency wait at every phase barrier). Peak live ~240 < 256-VGPR cap
// of __launch_bounds__(256,2). wqn/wkn/wvn stay late (would exceed cap).
// ---------------------------------------------------------------------------
template <bool FUSE>
__global__ void __launch_bounds__(256, 2) k_layer(
    const float* __restrict__ q, const float* __restrict__ k,
    const float* __restrict__ v,
    const float* __restrict__ Wo, const float* __restrict__ bo,
    const float* __restrict__ ln1g, const float* __restrict__ ln1b,
    const float* __restrict__ Wff1, const float* __restrict__ bff1,
    const float* __restrict__ Wff2, const float* __restrict__ bff2,
    const float* __restrict__ ln2g, const float* __restrict__ ln2b,
    const float* __restrict__ Wqn, const float* __restrict__ bqn,
    const float* __restrict__ Wkn, const float* __restrict__ bkn,
    const float* __restrict__ Wvn, const float* __restrict__ bvn,
    float* __restrict__ qo, float* __restrict__ ko, float* __restrict__ vo,
    float* __restrict__ x) {
    __shared__ float attS[2][D];
    __shared__ float xs[2][D];
    __shared__ float f1s[2][2 * D];
    __shared__ float ppA[4][2][192];
    __shared__ float ppB[4][2][192];
    int t = threadIdx.x, lane = t & 63, w = t >> 6, ch = lane;
    int b = blockIdx.x, n0 = blockIdx.y * 2;

    // ---- attention-critical loads issued first ----
    int bh = b * NH + w;
    const float* kb = k + (size_t)bh * N * DH;
    const float* vb = v + (size_t)bh * N * DH;
    const float4* qp0 = (const float4*)(q + ((size_t)bh * N + n0) * DH);
    const float4* qp1 = (const float4*)(q + ((size_t)bh * N + n0 + 1) * DH);
    float4 KA[4], VA[4], KB[4], VB[4];
    ATT_LOAD(KA, VA, 0);
    ATT_LOAD(KB, VB, 1);
    float4 qv0[4], qv1[4];
#pragma unroll
    for (int c = 0; c < 4; ++c) { qv0[c] = qp0[c]; qv1[c] = qp1[c]; }

    // ---- upfront weight prefetch: completes under attention compute ----
    float wo[16], wf1a[16], wf1b[16], wf2[32];
#pragma unroll
    for (int i = 0; i < 16; ++i) {
        int kk = w * 16 + i;
        wo[i]   = Wo[kk * D + ch];
        wf1a[i] = Wff1[kk * 2 * D + ch];
        wf1b[i] = Wff1[kk * 2 * D + D + ch];
    }
#pragma unroll
    for (int i = 0; i < 32; ++i) wf2[i] = Wff2[(w * 32 + i) * D + ch];

    size_t xi0 = ((size_t)(b * N + n0)) * D + ch;
    float xv0 = x[xi0], xv1 = x[xi0 + D];
    float bo_r = bo[ch], l1g = ln1g[ch], l1b = ln1b[ch];
    float bf1a = bff1[ch], bf1b = bff1[D + ch];
    float bf2_r = bff2[ch], l2g = ln2g[ch], l2b = ln2b[ch];

    float o0[DH], o1[DH];
#pragma unroll
    for (int d = 0; d < DH; ++d) { o0[d] = 0.f; o1[d] = 0.f; }
    float l0 = 0.f, l1 = 0.f;

    ATT_CHUNK(KA, VA);                   // compute 0
    ATT_LOAD(KA, VA, 2);                 // chunk 2 in flight
    ATT_CHUNK(KB, VB);                   // compute 1
    ATT_LOAD(KB, VB, 3);                 // chunk 3 in flight
    ATT_CHUNK(KA, VA);                   // compute 2
    ATT_CHUNK(KB, VB);                   // compute 3

    // ---- pin weight materialization here (loads done under attention) ----
#pragma unroll
    for (int i = 0; i < 16; ++i)
        asm volatile("" :: "v"(wo[i]), "v"(wf1a[i]), "v"(wf1b[i]));
#pragma unroll
    for (int i = 0; i < 32; ++i)
        asm volatile("" :: "v"(wf2[i]));

#pragma unroll
    for (int off = 32; off > 0; off >>= 1) {
        l0 += __shfl_xor(l0, off);
        l1 += __shfl_xor(l1, off);
    }
#pragma unroll
    for (int d = 0; d < DH; ++d) {
#pragma unroll
        for (int off = 32; off > 0; off >>= 1) {
            o0[d] += __shfl_xor(o0[d], off);
            o1[d] += __shfl_xor(o1[d], off);
        }
    }
    float rl0 = 1.f / l0, rl1 = 1.f / l1;
    if (lane < DH) {
        float sel0 = o0[0], sel1 = o1[0];
#pragma unroll
        for (int d = 1; d < DH; ++d)
            if (lane == d) { sel0 = o0[d]; sel1 = o1[d]; }
        attS[0][w * DH + lane] = sel0 * rl0;
        attS[1][w * DH + lane] = sel1 * rl1;
    }
    __syncthreads();

    // ---- O-proj (split-K-4, both tokens; weights already in regs) ----
    {
        float a0 = 0.f, a1 = 0.f;
#pragma unroll
        for (int i = 0; i < 16; ++i) {
            int kk = w * 16 + i;
            float wv = wo[i];
            a0 += attS[0][kk] * wv;
            a1 += attS[1][kk] * wv;
        }
        ppA[w][0][ch] = a0; ppA[w][1][ch] = a1;
    }
    __syncthreads();

    // ---- LN1 (both tokens, redundant per wave) ----
    float r0 = xv0 + bo_r + ppA[0][0][ch] + ppA[1][0][ch] + ppA[2][0][ch] + ppA[3][0][ch];
    float r1 = xv1 + bo_r + ppA[0][1][ch] + ppA[1][1][ch] + ppA[2][1][ch] + ppA[3][1][ch];
    float s0a = r0, q0a = r0 * r0, s1a = r1, q1a = r1 * r1;
#pragma unroll
    for (int off = 32; off > 0; off >>= 1) {
        s0a += __shfl_xor(s0a, off); q0a += __shfl_xor(q0a, off);
        s1a += __shfl_xor(s1a, off); q1a += __shfl_xor(q1a, off);
    }
    float mean10 = s0a * (1.0f / D), var10 = q0a * (1.0f / D) - mean10 * mean10;
    float mean11 = s1a * (1.0f / D), var11 = q1a * (1.0f / D) - mean11 * mean11;
    float x1_0 = l1g * (r0 - mean10) * rsqrtf(var10 + EPS) + l1b;
    float x1_1 = l1g * (r1 - mean11) * rsqrtf(var11 + EPS) + l1b;
    if (w == 0) xs[0][ch] = x1_0;
    if (w == 1) xs[1][ch] = x1_1;
    __syncthreads();

    // ---- FFN1 (split-K-4, both halves, both tokens; weights in regs) ----
    {
        float u0=0.f, g0=0.f, u1=0.f, g1=0.f;
#pragma unroll
        for (int i = 0; i < 16; ++i) {
            int kk = w * 16 + i;
            float xx0 = xs[0][kk], xx1 = xs[1][kk];
            u0 += xx0 * wf1a[i]; g0 += xx0 * wf1b[i];
            u1 += xx1 * wf1a[i]; g1 += xx1 * wf1b[i];
        }
        ppB[w][0][ch] = u0; ppB[w][0][64 + ch] = g0;
        ppB[w][1][ch] = u1; ppB[w][1][64 + ch] = g1;
    }
    __syncthreads();

    // ---- ReLU combine -> f1s ----
    {
        float a00 = fmaxf(bf1a + ppB[0][0][ch] + ppB[1][0][ch] + ppB[2][0][ch] + ppB[3][0][ch], 0.f);
        float a01 = fmaxf(bf1b + ppB[0][0][64+ch] + ppB[1][0][64+ch] + ppB[2][0][64+ch] + ppB[3][0][64+ch], 0.f);
        float a10 = fmaxf(bf1a + ppB[0][1][ch] + ppB[1][1][ch] + ppB[2][1][ch] + ppB[3][1][ch], 0.f);
        float a11 = fmaxf(bf1b + ppB[0][1][64+ch] + ppB[1][1][64+ch] + ppB[2][1][64+ch] + ppB[3][1][64+ch], 0.f);
        if (w == 0) { f1s[0][ch] = a00; f1s[0][64 + ch] = a01; }
        if (w == 1) { f1s[1][ch] = a10; f1s[1][64 + ch] = a11; }
    }
    __syncthreads();

    // ---- FFN2 (split-K-4 over 128; weights in regs) + prefetch next QKV ----
    {
        float e0 = 0.f, e1 = 0.f;
#pragma unroll
        for (int i = 0; i < 32; ++i) {
            int kk = w * 32 + i;
            float xx0 = f1s[0][kk], xx1 = f1s[1][kk];
            e0 += xx0 * wf2[i];
            e1 += xx1 * wf2[i];
        }
        ppA[w][0][ch] = e0; ppA[w][1][ch] = e1;
    }
    float wqn[16], wkn[16], wvn[16];
    if (FUSE) {
#pragma unroll
        for (int i = 0; i < 16; ++i) {
            int kk = w * 16 + i;
            wqn[i] = Wqn[kk * D + ch];
            wkn[i] = Wkn[kk * D + ch];
            wvn[i] = Wvn[kk * D + ch];
        }
    }
    __syncthreads();

    // ---- LN2 (both tokens, redundant per wave) ----
    float o2_0 = bf2_r + ppA[0][0][ch] + ppA[1][0][ch] + ppA[2][0][ch] + ppA[3][0][ch];
    float o2_1 = bf2_r + ppA[0][1][ch] + ppA[1][1][ch] + ppA[2][1][ch] + ppA[3][1][ch];
    float r20 = x1_0 + o2_0, r21 = x1_1 + o2_1;
    float s0b = r20, q0b = r20 * r20, s1b = r21, q1b = r21 * r21;
#pragma unroll
    for (int off = 32; off > 0; off >>= 1) {
        s0b += __shfl_xor(s0b, off); q0b += __shfl_xor(q0b, off);
        s1b += __shfl_xor(s1b, off); q1b += __shfl_xor(q1b, off);
    }
    float mean20 = s0b * (1.0f / D), var20 = q0b * (1.0f / D) - mean20 * mean20;
    float mean21 = s1b * (1.0f / D), var21 = q1b * (1.0f / D) - mean21 * mean21;
    float xn0 = l2g * (r20 - mean20) * rsqrtf(var20 + EPS) + l2b;
    float xn1 = l2g * (r21 - mean21) * rsqrtf(var21 + EPS) + l2b;
    if (w == 0) x[xi0] = xn0;
    if (w == 1) x[xi0 + D] = xn1;

    // ---- fused next-layer QKV ----
    if (FUSE) {
        if (w == 0) xs[0][ch] = xn0;
        if (w == 1) xs[1][ch] = xn1;
        __syncthreads();
        float aq0=0.f, ak0=0.f, av0=0.f, aq1=0.f, ak1=0.f, av1=0.f;
#pragma unroll
        for (int i = 0; i < 16; ++i) {
            int kk = w * 16 + i;
            float xx0 = xs[0][kk], xx1 = xs[1][kk];
            aq0 += xx0 * wqn[i]; ak0 += xx0 * wkn[i]; av0 += xx0 * wvn[i];
            aq1 += xx1 * wqn[i]; ak1 += xx1 * wkn[i]; av1 += xx1 * wvn[i];
        }
        ppB[w][0][ch] = aq0; ppB[w][0][64 + ch] = ak0; ppB[w][0][128 + ch] = av0;
        ppB[w][1][ch] = aq1; ppB[w][1][64 + ch] = ak1; ppB[w][1][128 + ch] = av1;
        __syncthreads();
        if (w < 3) {
            int o = w * 64;
            int head = ch >> 4, dh = ch & (DH - 1);
#pragma unroll
            for (int tk = 0; tk < 2; ++tk) {
                float val = ppB[0][tk][o+ch] + ppB[1][tk][o+ch] + ppB[2][tk][o+ch] + ppB[3][tk][o+ch];
                size_t oidx = (((size_t)(b * NH + head)) * N + (n0 + tk)) * DH + dh;
                if (w == 0) qo[oidx] = val + bqn[ch];
                else if (w == 1) ko[oidx] = val + bkn[ch];
                else vo[oidx] = val + bvn[ch];
            }
        }
    }
}

extern "C" void kernel_launch(void* const* d_in, const int* in_sizes, int n_in,
                              void* d_out, int out_size, void* d_ws, size_t ws_size,
                              hipStream_t stream) {
    const float* feature = (const float*)d_in[0];
    const float* W1   = (const float*)d_in[1];
    const float* b1   = (const float*)d_in[2];
    const float* mw   = (const float*)d_in[3];
    const float* mb   = (const float*)d_in[4];
    const float* bn_g = (const float*)d_in[5];
    const float* bn_b = (const float*)d_in[6];
    const float* Wq   = (const float*)d_in[7];
    const float* bq   = (const float*)d_in[8];
    const float* Wk   = (const float*)d_in[9];
    const float* bk   = (const float*)d_in[10];
    const float* Wv   = (const float*)d_in[11];
    const float* bv   = (const float*)d_in[12];
    const float* Wo   = (const float*)d_in[13];
    const float* bo   = (const float*)d_in[14];
    const float* ln1g = (const float*)d_in[15];
    const float* ln1b = (const float*)d_in[16];
    const float* Wff1 = (const float*)d_in[17];
    const float* bff1 = (const float*)d_in[18];
    const float* Wff2 = (const float*)d_in[19];
    const float* bff2 = (const float*)d_in[20];
    const float* ln2g = (const float*)d_in[21];
    const float* ln2b = (const float*)d_in[22];

    float* ws    = (float*)d_ws;
    float* rs    = ws;                     // B*N*NH = 4096
    float* bnacc = rs + B * N * NH;        // 128
    float* h     = bnacc + 128;            // B*N*D
    float* q     = h + B * N * D;          // B*N*D
    float* k0    = q + B * N * D;
    float* v0    = k0 + B * N * D;
    float* k1    = v0 + B * N * D;
    float* v1    = k1 + B * N * D;
    float* x     = (float*)d_out;          // running (B,N,D) activation

    k_rowsum<<<256, 512, 0, stream>>>(feature, W1, b1, mw, mb, rs, bnacc);
    k_aggregate<<<256, 512, 0, stream>>>(feature, W1, b1, mw, mb, rs, h, bnacc);
    k_qkv0<<<dim3(B, N / 2), 256, 0, stream>>>(h, bnacc, bn_g, bn_b,
                                               Wq, bq, Wk, bk, Wv, bv, x, q, k0, v0);
    // layer 0 (fused layer-1 QKV into q / k1 / v1), then layer 1
    k_layer<true><<<dim3(B, N / 2), 256, 0, stream>>>(q, k0, v0,
        Wo, bo, ln1g, ln1b, Wff1, bff1, Wff2, bff2, ln2g, ln2b,
        Wq + (size_t)D * D, bq + D, Wk + (size_t)D * D, bk + D,
        Wv + (size_t)D * D, bv + D, q, k1, v1, x);
    k_layer<false><<<dim3(B, N / 2), 256, 0, stream>>>(q, k1, v1,
        Wo + (size_t)D * D, bo + D, ln1g + D, ln1b + D,
        Wff1 + (size_t)D * 2 * D, bff1 + 2 * D,
        Wff2 + (size_t)2 * D * D, bff2 + D, ln2g + D, ln2b + D,
        nullptr, nullptr, nullptr, nullptr, nullptr, nullptr,
        nullptr, nullptr, nullptr, x);
}